// Round 3
// baseline (75.287 us; speedup 1.0000x reference)
//
#include <hip/hip_runtime.h>
#include <stdint.h>

#define B_  16
#define H_  512
#define W_  512
#define HW_ (H_*W_)
#define N_  (B_*HW_)

#define TX 64
#define TY 16
#define SW 80          // storage stride (floats / bytes), col0 = tx0-8, 20 quads
#define RA 26          // gray / t rows,  row0 = ty0-5
#define RB 22          // blur rows,      row0 = ty0-3
#define RC 20          // mag/dir rows,   row0 = ty0-2
#define RD 18          // E rows,         row0 = ty0-1

#define G0 0.054488685f
#define G1 0.244201342f
#define G2 0.402619947f

// nibble LUTs: (dy+1), (dx+1) for direction p = 0..7 (E,NE,N,NW,W,SW,S,SE)
#define DYP 0x22210001u
#define DXP 0x21000122u

// byte extract from 3-word row window (idx in [-1,4], compile-time)
#define EB(wm,wc,wp,idx) ((idx) < 0 ? (int)(((wm) >> 24) & 255u) \
                        : ((idx) > 3 ? (int)((wp) & 255u) \
                        : (int)(((wc) >> (8*(idx))) & 255u)))

__device__ __forceinline__ int reflect512(int i) {
    i = i < 0 ? -i : i;
    return i > 511 ? 1022 - i : i;
}
__device__ __forceinline__ int clamp511(int v) {
    return v < 0 ? 0 : (v > 511 ? 511 : v);
}

__device__ __forceinline__ void sobel_px(float a00, float a01, float a02,
                                         float a10, float a12,
                                         float a20, float a21, float a22,
                                         float& m, int& k) {
    float gxv = ((a02 + 2.f*a12 + a22) - (a00 + 2.f*a10 + a20)) * 0.125f;
    float gyv = ((a20 + 2.f*a21 + a22) - (a00 + 2.f*a01 + a02)) * 0.125f;
    m = sqrtf(gxv*gxv + gyv*gyv + 1e-6f);
    float agx = fabsf(gxv), agy = fabsf(gyv);
    if      (agy <= 0.41421356f * agx) k = (gxv >= 0.f) ? 0 : 4;
    else if (agy >= 2.41421356f * agx) k = (gyv >  0.f) ? 2 : 6;
    else k = (gyv > 0.f) ? ((gxv > 0.f) ? 1 : 3) : ((gxv > 0.f) ? 7 : 5);
}

__global__ __launch_bounds__(256)
void k_canny(const float* __restrict__ pred, const float* __restrict__ sketch,
             const float* __restrict__ matte, float* __restrict__ out) {
    __shared__ __align__(16) union { float g[RA][SW]; float mag[RC][SW]; } u1;
    __shared__ __align__(16) union {
        float t[RA][SW];
        struct { uint8_t dir[RC][SW]; uint8_t e[RD][SW]; } de;
    } u2;
    __shared__ __align__(16) float sBlur[RB][SW];
    __shared__ float wsum[4];

    const int tid = threadIdx.x;
    const int tx0 = blockIdx.x * TX;
    const int ty0 = blockIdx.y * TY;
    const int b   = blockIdx.z;

    const float* pb = pred   + (size_t)b * 3 * HW_;
    const float* mb = matte  + (size_t)b * HW_;
    const float* sb = sketch + (size_t)b * HW_;

    // ---- A: gray = mean3(pred)*matte, reflect-mapped, [26][80] ----
    for (int u = tid; u < RA*20; u += 256) {
        int r = u / 20, q = u - r*20;
        int gy = ty0 - 5 + r;
        int gx = tx0 - 8 + q*4;
        int ys = reflect512(gy);
        float4 res;
        if (gx >= 0 && gx + 3 < W_) {
            const float* base = pb + ys*W_ + gx;
            float4 p0 = *(const float4*)(base);
            float4 p1 = *(const float4*)(base + HW_);
            float4 p2 = *(const float4*)(base + 2*HW_);
            float4 m4 = *(const float4*)(mb + ys*W_ + gx);
            res.x = (p0.x+p1.x+p2.x)*m4.x*(1.f/3.f);
            res.y = (p0.y+p1.y+p2.y)*m4.y*(1.f/3.f);
            res.z = (p0.z+p1.z+p2.z)*m4.z*(1.f/3.f);
            res.w = (p0.w+p1.w+p2.w)*m4.w*(1.f/3.f);
        } else {
            float tmp[4];
            #pragma unroll
            for (int e = 0; e < 4; ++e) {
                int xs = reflect512(gx + e);
                int o  = ys*W_ + xs;
                tmp[e] = (pb[o] + pb[o+HW_] + pb[o+2*HW_]) * mb[o] * (1.f/3.f);
            }
            res.x = tmp[0]; res.y = tmp[1]; res.z = tmp[2]; res.w = tmp[3];
        }
        *(float4*)&u1.g[r][q*4] = res;
    }
    __syncthreads();

    // ---- B1: horizontal gaussian -> t  [26][80] ----
    for (int u = tid; u < RA*20; u += 256) {
        int r = u / 20, q = u - r*20;
        int gx = tx0 - 8 + q*4;
        int qm = (q > 0)  ? q-1 : 0;
        int qp = (q < 19) ? q+1 : 19;
        float4 res;
        if (gx - 2 >= 0 && gx + 5 < W_) {
            float4 fa = *(float4*)&u1.g[r][qm*4];
            float4 fb = *(float4*)&u1.g[r][q*4];
            float4 fc = *(float4*)&u1.g[r][qp*4];
            res.x = G0*fa.z + G1*fa.w + G2*fb.x + G1*fb.y + G0*fb.z;
            res.y = G0*fa.w + G1*fb.x + G2*fb.y + G1*fb.z + G0*fb.w;
            res.z = G0*fb.x + G1*fb.y + G2*fb.z + G1*fb.w + G0*fc.x;
            res.w = G0*fb.y + G1*fb.z + G2*fb.w + G1*fc.x + G0*fc.y;
        } else {
            float tmp[4];
            #pragma unroll
            for (int e = 0; e < 4; ++e) {
                int xc = clamp511(gx + e);
                float a;
                a  = G0 * u1.g[r][reflect512(xc-2) - (tx0-8)];
                a += G1 * u1.g[r][reflect512(xc-1) - (tx0-8)];
                a += G2 * u1.g[r][xc - (tx0-8)];
                a += G1 * u1.g[r][reflect512(xc+1) - (tx0-8)];
                a += G0 * u1.g[r][reflect512(xc+2) - (tx0-8)];
                tmp[e] = a;
            }
            res.x = tmp[0]; res.y = tmp[1]; res.z = tmp[2]; res.w = tmp[3];
        }
        *(float4*)&u2.t[r][q*4] = res;
    }
    __syncthreads();

    // ---- B2: vertical gaussian -> blur [22][80] ----
    for (int u = tid; u < RB*20; u += 256) {
        int r = u / 20, q = u - r*20;
        int gy = ty0 - 3 + r;
        int yc = clamp511(gy);
        int l0 = reflect512(yc-2) - (ty0-5);
        int l1 = reflect512(yc-1) - (ty0-5);
        int l2 = yc - (ty0-5);
        int l3 = reflect512(yc+1) - (ty0-5);
        int l4 = reflect512(yc+2) - (ty0-5);
        float4 t0 = *(float4*)&u2.t[l0][q*4];
        float4 t1 = *(float4*)&u2.t[l1][q*4];
        float4 t2 = *(float4*)&u2.t[l2][q*4];
        float4 t3 = *(float4*)&u2.t[l3][q*4];
        float4 t4 = *(float4*)&u2.t[l4][q*4];
        float4 res;
        res.x = G0*t0.x + G1*t1.x + G2*t2.x + G1*t3.x + G0*t4.x;
        res.y = G0*t0.y + G1*t1.y + G2*t2.y + G1*t3.y + G0*t4.y;
        res.z = G0*t0.z + G1*t1.z + G2*t2.z + G1*t3.z + G0*t4.z;
        res.w = G0*t0.w + G1*t1.w + G2*t2.w + G1*t3.w + G0*t4.w;
        *(float4*)&sBlur[r][q*4] = res;
    }
    __syncthreads();

    // ---- C: sobel -> mag [20][80] (quads 1..18) + dir ----
    for (int u = tid; u < RC*18; u += 256) {
        int r = u / 18, q = (u - r*18) + 1;
        int gy = ty0 - 2 + r;
        int gx = tx0 - 8 + q*4;
        float mg[4] = {0.f, 0.f, 0.f, 0.f};
        uint32_t dpack = 0;
        if (gy >= 0 && gy < H_) {
            int r0 = clamp511(gy-1) - (ty0-3);
            int r1 = gy - (ty0-3);
            int r2 = clamp511(gy+1) - (ty0-3);
            if (gx - 1 >= 0 && gx + 4 < W_) {
                float4 a0 = *(float4*)&sBlur[r0][(q-1)*4];
                float4 a1 = *(float4*)&sBlur[r0][q*4];
                float4 a2 = *(float4*)&sBlur[r0][(q+1)*4];
                float4 b0 = *(float4*)&sBlur[r1][(q-1)*4];
                float4 b1 = *(float4*)&sBlur[r1][q*4];
                float4 b2 = *(float4*)&sBlur[r1][(q+1)*4];
                float4 c0 = *(float4*)&sBlur[r2][(q-1)*4];
                float4 c1 = *(float4*)&sBlur[r2][q*4];
                float4 c2 = *(float4*)&sBlur[r2][(q+1)*4];
                float ta[12] = {a0.x,a0.y,a0.z,a0.w, a1.x,a1.y,a1.z,a1.w, a2.x,a2.y,a2.z,a2.w};
                float tb[12] = {b0.x,b0.y,b0.z,b0.w, b1.x,b1.y,b1.z,b1.w, b2.x,b2.y,b2.z,b2.w};
                float tc[12] = {c0.x,c0.y,c0.z,c0.w, c1.x,c1.y,c1.z,c1.w, c2.x,c2.y,c2.z,c2.w};
                #pragma unroll
                for (int e = 0; e < 4; ++e) {
                    float m; int k;
                    sobel_px(ta[e+3], ta[e+4], ta[e+5],
                             tb[e+3],          tb[e+5],
                             tc[e+3], tc[e+4], tc[e+5], m, k);
                    mg[e] = m;
                    dpack |= (uint32_t)k << (8*e);
                }
            } else {
                #pragma unroll
                for (int e = 0; e < 4; ++e) {
                    int gxe = gx + e;
                    if (gxe >= 0 && gxe < W_) {
                        int cm = clamp511(gxe-1) - (tx0-8);
                        int cc = gxe - (tx0-8);
                        int cp = clamp511(gxe+1) - (tx0-8);
                        float m; int k;
                        sobel_px(sBlur[r0][cm], sBlur[r0][cc], sBlur[r0][cp],
                                 sBlur[r1][cm],                sBlur[r1][cp],
                                 sBlur[r2][cm], sBlur[r2][cc], sBlur[r2][cp], m, k);
                        mg[e] = m;
                        dpack |= (uint32_t)k << (8*e);
                    }
                }
            }
        }
        *(float4*)&u1.mag[r][q*4] = make_float4(mg[0], mg[1], mg[2], mg[3]);
        *(uint32_t*)&u2.de.dir[r][q*4] = dpack;
    }
    __syncthreads();

    // ---- D: NMS + double threshold -> E class [18][80] (quads 1..18) ----
    for (int u = tid; u < RD*18; u += 256) {
        int r = u / 18, q = (u - r*18) + 1;
        uint32_t dw = *(uint32_t*)&u2.de.dir[r+1][q*4];
        float4 mc = *(float4*)&u1.mag[r+1][q*4];
        float mcv[4] = {mc.x, mc.y, mc.z, mc.w};
        uint32_t epack = 0;
        #pragma unroll
        for (int e = 0; e < 4; ++e) {
            float m = mcv[e];
            int p  = (int)((dw >> (8*e)) & 7u);
            int qd = (p + 4) & 7;
            int dy1 = (int)((DYP >> (p*4))  & 7u) - 1;
            int dx1 = (int)((DXP >> (p*4))  & 7u) - 1;
            int dy2 = (int)((DYP >> (qd*4)) & 7u) - 1;
            int dx2 = (int)((DXP >> (qd*4)) & 7u) - 1;
            float n1 = u1.mag[r+1+dy1][q*4+e+dx1];
            float n2 = u1.mag[r+1+dy2][q*4+e+dx2];
            float mm = (fminf(m - n1, m - n2) > 0.f) ? m : 0.f;
            int cls = (mm > 0.1f) + (mm > 0.2f);
            epack |= (uint32_t)cls << (8*e);
        }
        *(uint32_t*)&u2.de.e[r][q*4] = epack;
    }
    __syncthreads();

    // ---- E: hysteresis promotion (1 sweep) + MSE contribution ----
    {
        int r16 = tid >> 4, q16 = tid & 15;
        int gy = ty0 + r16, gx = tx0 + q16*4;
        int er = r16;                 // row (gy-1) in E coords
        int bc = q16*4 + 8;
        uint32_t w0m = *(uint32_t*)&u2.de.e[er  ][bc-4];
        uint32_t w0c = *(uint32_t*)&u2.de.e[er  ][bc  ];
        uint32_t w0p = *(uint32_t*)&u2.de.e[er  ][bc+4];
        uint32_t w1m = *(uint32_t*)&u2.de.e[er+1][bc-4];
        uint32_t w1c = *(uint32_t*)&u2.de.e[er+1][bc  ];
        uint32_t w1p = *(uint32_t*)&u2.de.e[er+1][bc+4];
        uint32_t w2m = *(uint32_t*)&u2.de.e[er+2][bc-4];
        uint32_t w2c = *(uint32_t*)&u2.de.e[er+2][bc  ];
        uint32_t w2p = *(uint32_t*)&u2.de.e[er+2][bc+4];
        int cls[4] = { (int)(w1c & 255u), (int)((w1c>>8) & 255u),
                       (int)((w1c>>16) & 255u), (int)((w1c>>24) & 255u) };
        uint32_t tw = w1c ^ 0x01010101u;
        if ((tw - 0x01010101u) & ~tw & 0x80808080u) {   // any weak byte
            #pragma unroll
            for (int e = 0; e < 4; ++e) {
                if (cls[e] == 1) {
                    bool pr =
                        (EB(w0m,w0c,w0p,e-1) == 2) | (EB(w0m,w0c,w0p,e) == 2) | (EB(w0m,w0c,w0p,e+1) == 2) |
                        (EB(w1m,w1c,w1p,e-1) == 2) |                            (EB(w1m,w1c,w1p,e+1) == 2) |
                        (EB(w2m,w2c,w2p,e-1) == 2) | (EB(w2m,w2c,w2p,e) == 2) | (EB(w2m,w2c,w2p,e+1) == 2);
                    if (pr) cls[e] = 2;
                }
            }
        }
        float4 s4 = *(const float4*)(sb + gy*W_ + gx);
        float4 m4 = *(const float4*)(mb + gy*W_ + gx);
        float lacc = 0.f, tt, d;
        tt = fminf(fmaxf(s4.x*m4.x, 0.f), 1.f); d = 0.5f*(float)cls[0] - tt; lacc += d*d;
        tt = fminf(fmaxf(s4.y*m4.y, 0.f), 1.f); d = 0.5f*(float)cls[1] - tt; lacc += d*d;
        tt = fminf(fmaxf(s4.z*m4.z, 0.f), 1.f); d = 0.5f*(float)cls[2] - tt; lacc += d*d;
        tt = fminf(fmaxf(s4.w*m4.w, 0.f), 1.f); d = 0.5f*(float)cls[3] - tt; lacc += d*d;

        #pragma unroll
        for (int off = 32; off > 0; off >>= 1)
            lacc += __shfl_down(lacc, off, 64);
        if ((tid & 63) == 0) wsum[tid >> 6] = lacc;
    }
    __syncthreads();
    if (tid == 0)
        atomicAdd(out, (wsum[0] + wsum[1] + wsum[2] + wsum[3]) * (1.0f / (float)N_));
}

extern "C" void kernel_launch(void* const* d_in, const int* in_sizes, int n_in,
                              void* d_out, int out_size, void* d_ws, size_t ws_size,
                              hipStream_t stream) {
    const float* pred   = (const float*)d_in[0];
    const float* sketch = (const float*)d_in[1];
    const float* matte  = (const float*)d_in[2];
    float* out = (float*)d_out;

    hipMemsetAsync(d_out, 0, sizeof(float), stream);
    dim3 blk(256);
    dim3 grd(W_/TX, H_/TY, B_);   // (8, 32, 16)
    k_canny<<<grd, blk, 0, stream>>>(pred, sketch, matte, out);
}